// Round 9
// baseline (122.380 us; speedup 1.0000x reference)
//
#include <hip/hip_runtime.h>

// Shapes (fixed by the reference): B=N=16, C=256, D=512, H=W=16 (HW=256)
#define B_  16
#define N_  16
#define C_  256
#define D_  512
#define HW_ 256

typedef float f32x4 __attribute__((ext_vector_type(4)));

// ws layout (float offsets) — every slot written every call; no memset needed.
#define WS_S      0        // 4096 : s[b,hw]
#define WS_M      4096     // 16   : per-b softmax max (corner max)
#define WS_ZP     4112     // 512  : Z partials, 32 per b

__device__ __forceinline__ float corner(float tmax, float tmin, float smax, float smin) {
  return fmaxf(fmaxf(tmax * smax, tmax * smin), fmaxf(tmin * smax, tmin * smin));
}

// ---------------- kA: 32 blocks x 512 threads ----------------
// blocks 0..15 : s[b,:] + m_b (byte-identical to R8's proven s-block)
// blocks 16..31: bv-block for b: vfmean -> vpmean (LDS) -> final[b,:] to out
__global__ void kA(const float* __restrict__ vf, const float* __restrict__ vw,
                   const float* __restrict__ vb, const float* __restrict__ te,
                   const float* __restrict__ mtf, const float* __restrict__ iw,
                   const float* __restrict__ ib, float* __restrict__ ws,
                   float* __restrict__ out) {
  int bid = blockIdx.x, tid = threadIdx.x;
  int w = tid >> 6, lane = tid & 63;

  if (bid < 16) {
    int b = bid;
    __shared__ float pcw[8][256];     // colsum partials
    __shared__ float cw[256];
    __shared__ float sh2[2][256];
    __shared__ float r0[8], r1[8], r2[8], r3[8], r4[8];

    // --- te min/max + sum(vb) ---
    float mx = -1e30f, mn = 1e30f;
    #pragma unroll
    for (int i = tid; i < N_ * D_; i += 512) {
      float v = te[i];
      mx = fmaxf(mx, v); mn = fminf(mn, v);
    }
    float sb = vb[tid];
    for (int m = 32; m; m >>= 1) {
      mx = fmaxf(mx, __shfl_xor(mx, m));
      mn = fminf(mn, __shfl_xor(mn, m));
      sb += __shfl_xor(sb, m);
    }

    // --- colsum: cw[c] = sum_d vw[d,c]; depth 64 via 8 d-groups, float4 ---
    {
      const float4* vw4 = (const float4*)vw;     // [512][64]
      int dg = w, c4 = tid & 63;
      float4 p = make_float4(0.f, 0.f, 0.f, 0.f);
      #pragma unroll 8
      for (int d = dg * 64; d < dg * 64 + 64; ++d) {
        float4 v = vw4[d * 64 + c4];
        p.x += v.x; p.y += v.y; p.z += v.z; p.w += v.w;
      }
      pcw[dg][c4 * 4 + 0] = p.x;
      pcw[dg][c4 * 4 + 1] = p.y;
      pcw[dg][c4 * 4 + 2] = p.z;
      pcw[dg][c4 * 4 + 3] = p.w;
    }
    if ((tid & 63) == 0) { r0[w] = mx; r1[w] = mn; r2[w] = sb; }
    __syncthreads();
    float tmax = r0[0], tmin = r1[0]; sb = r2[0];
    #pragma unroll
    for (int k = 1; k < 8; ++k) {
      tmax = fmaxf(tmax, r0[k]); tmin = fminf(tmin, r1[k]); sb += r2[k];
    }
    if (tid < 256) {
      float a = 0.f;
      #pragma unroll
      for (int k = 0; k < 8; ++k) a += pcw[k][tid];
      cw[tid] = a;
    }
    __syncthreads();

    // --- s[b,hw]: depth-128 dot, 2 c-halves per hw ---
    {
      int hw = tid & 255, ch = tid >> 8;
      const float* vfb = vf + (size_t)b * C_ * HW_;
      float acc = 0.f;
      #pragma unroll 4
      for (int c = ch * 128; c < ch * 128 + 128; ++c)
        acc += vfb[c * HW_ + hw] * cw[c];
      sh2[ch][hw] = acc;
    }
    __syncthreads();

    float sv = 0.f;
    if (tid < 256) {
      sv = sh2[0][tid] + sh2[1][tid] + sb;
      ws[WS_S + b * HW_ + tid] = sv;
    }
    float smx = (tid < 256) ? sv : -1e30f;
    float smn = (tid < 256) ? sv :  1e30f;
    for (int m = 32; m; m >>= 1) {
      smx = fmaxf(smx, __shfl_xor(smx, m));
      smn = fminf(smn, __shfl_xor(smn, m));
    }
    if ((tid & 63) == 0) { r3[w] = smx; r4[w] = smn; }
    __syncthreads();
    if (tid == 0) {
      smx = fmaxf(fmaxf(r3[0], r3[1]), fmaxf(r3[2], r3[3]));
      smn = fminf(fminf(r4[0], r4[1]), fminf(r4[2], r4[3]));
      ws[WS_M + b] = corner(tmax, tmin, smx, smn);
    }
    return;
  }

  // ---- bv-block: vfmean -> vpmean (LDS) -> final[b,:] ----
  {
    int b = bid - 16;
    __shared__ __align__(16) float vfm[C_];   // vfmean[b,:]
    __shared__ __align__(16) float pm[D_];    // vpmean[b,:]
    __shared__ __align__(16) float aL[D_];    // mtf[b,:]

    // vfmean: wave w reduces rows c = w*32 .. w*32+31 (coalesced float4)
    #pragma unroll 4
    for (int r8 = 0; r8 < 32; ++r8) {
      int c = w * 32 + r8;
      float4 v = ((const float4*)(vf + ((size_t)b * C_ + c) * HW_))[lane];
      float s4 = v.x + v.y + v.z + v.w;
      for (int m = 32; m; m >>= 1) s4 += __shfl_xor(s4, m);
      if (lane == 0) vfm[c] = s4 * (1.0f / HW_);
    }
    aL[tid] = mtf[b * D_ + tid];
    __syncthreads();

    // vpmean[b,dd] = dot(vfm, vw[dd,:]) + vb[dd]
    {
      int dd = tid;
      float acc = vb[dd];
      const f32x4* row4 = (const f32x4*)(vw + (size_t)dd * C_);
      const f32x4* v4   = (const f32x4*)vfm;
      #pragma unroll 8
      for (int c4 = 0; c4 < C_ / 4; ++c4) {
        f32x4 wv = row4[c4], av = v4[c4];
        acc += av.x * wv.x + av.y * wv.y + av.z * wv.z + av.w * wv.w;
      }
      pm[dd] = acc;
    }
    __syncthreads();

    // final[b,d] = dot(aL, iw[d,0:512]) + dot(pm, iw[d,512:1024]) + ib[d]
    {
      int d = tid;
      float acc = ib[d];
      const f32x4* row4 = (const f32x4*)(iw + (size_t)d * (2 * D_));
      const f32x4* a4 = (const f32x4*)aL;
      const f32x4* p4 = (const f32x4*)pm;
      #pragma unroll 8
      for (int c4 = 0; c4 < D_ / 4; ++c4) {
        f32x4 w1 = row4[c4],            av = a4[c4];
        f32x4 w2 = row4[D_ / 4 + c4],   pv = p4[c4];
        acc += av.x * w1.x + av.y * w1.y + av.z * w1.z + av.w * w1.w;
        acc += pv.x * w2.x + pv.y * w2.y + pv.z * w2.z + pv.w * w2.w;
      }
      out[b * D_ + d] = acc;
    }
  }
}

// ---------------- kB: Z partials, 512 blocks x 256 threads -----------------
// f32x4 LDS reads (64 ds_read_b128 instead of 256 ds_read_b32), 4 accums.
__global__ __launch_bounds__(256)
void kB(const float* __restrict__ te, float* __restrict__ ws) {
  int bid = blockIdx.x, tid = threadIdx.x;
  int b = bid >> 5, chunk = bid & 31;
  __shared__ __align__(16) float sl[HW_];
  __shared__ float part[4];
  sl[tid] = ws[WS_S + b * HW_ + tid];
  __syncthreads();
  float m = ws[WS_M + b];
  float t = te[chunk * 256 + tid];
  const f32x4* sl4 = (const f32x4*)sl;
  float a0 = 0.f, a1 = 0.f, a2 = 0.f, a3 = 0.f;
  #pragma unroll 8
  for (int h = 0; h < HW_ / 4; ++h) {
    f32x4 s4 = sl4[h];
    a0 += __expf(t * s4.x - m);
    a1 += __expf(t * s4.y - m);
    a2 += __expf(t * s4.z - m);
    a3 += __expf(t * s4.w - m);
  }
  float z = (a0 + a1) + (a2 + a3);
  for (int mm = 32; mm; mm >>= 1) z += __shfl_xor(z, mm);
  if ((tid & 63) == 0) part[tid >> 6] = z;
  __syncthreads();
  if (tid == 0) ws[WS_ZP + bid] = part[0] + part[1] + part[2] + part[3];
}

// ---------------- kD: attn only, 2048 blocks x 64 rows, nt stores ----------
__global__ __launch_bounds__(256)
void kD(const float* __restrict__ te, const float* __restrict__ ws,
        float* __restrict__ out) {
  int bid = blockIdx.x, tid = threadIdx.x;
  int r0 = bid * 64;                  // global row = b*8192 + nd
  int b = r0 >> 13;                   // 64-row blocks never straddle a b
  __shared__ __align__(16) float sl[HW_];
  __shared__ float sinvZ;
  sl[tid] = ws[WS_S + b * HW_ + tid];
  if (tid < 32) {
    float pz = ws[WS_ZP + b * 32 + tid];
    #pragma unroll
    for (int m = 16; m; m >>= 1) pz += __shfl_xor(pz, m);
    if (tid == 0) sinvZ = 1.0f / pz;
  }
  __syncthreads();
  float m = ws[WS_M + b];
  float invZ = sinvZ;
  int lane = tid & 63;
  int w = tid >> 6;
  float4 sv = ((const float4*)sl)[lane];
  float* attn = out + N_ * D_;        // skip final (8192 floats)
  #pragma unroll 4
  for (int k = 0; k < 16; ++k) {
    int row = r0 + w + k * 4;
    float t = te[row & (N_ * D_ - 1)];
    f32x4 o;
    o.x = __expf(t * sv.x - m) * invZ;
    o.y = __expf(t * sv.y - m) * invZ;
    o.z = __expf(t * sv.z - m) * invZ;
    o.w = __expf(t * sv.w - m) * invZ;
    __builtin_nontemporal_store(o, (f32x4*)(attn + (size_t)row * HW_) + lane);
  }
}

extern "C" void kernel_launch(void* const* d_in, const int* in_sizes, int n_in,
                              void* d_out, int out_size, void* d_ws, size_t ws_size,
                              hipStream_t stream) {
  const float* mtf = (const float*)d_in[0];  // masked_text_features [16,512]
  const float* vf  = (const float*)d_in[1];  // visual_features [16,256,16,16]
  const float* te  = (const float*)d_in[2];  // text_embeddings [16,512]
  const float* vw  = (const float*)d_in[3];  // visual_proj_w [512,256]
  const float* vb  = (const float*)d_in[4];  // visual_proj_b [512]
  const float* iw  = (const float*)d_in[5];  // interaction_w [512,1024]
  const float* ib  = (const float*)d_in[6];  // interaction_b [512]
  float* out = (float*)d_out;
  float* ws  = (float*)d_ws;

  kA<<<32,   512, 0, stream>>>(vf, vw, vb, te, mtf, iw, ib, ws, out);
  kB<<<512,  256, 0, stream>>>(te, ws);
  kD<<<2048, 256, 0, stream>>>(te, ws, out);
}

// Round 10
// 69.989 us; speedup vs baseline: 1.7486x; 1.7486x over previous
//
#include <hip/hip_runtime.h>

// Shapes (fixed by the reference): B=N=16, C=256, D=512, H=W=16 (HW=256)
#define B_  16
#define N_  16
#define C_  256
#define D_  512
#define HW_ 256

typedef float f32x4 __attribute__((ext_vector_type(4)));

// ws layout (float offsets)
#define WS_SP     0         // 32768 : s partials [16][8][256]
#define WS_S      32768     // 4096  : s[b,hw] (written by chunk-0 Z-blocks)
#define WS_M      36864     // 16    : per-b softmax max
#define WS_TMAX   36880     // 1
#define WS_TMIN   36881     // 1
#define WS_VFMEAN 36884     // 4096
#define WS_VPMEAN 40980     // 8192
#define WS_ZP     49172     // 512   : Z partials, 32 per b

__device__ __forceinline__ float corner(float tmax, float tmin, float smax, float smin) {
  return fmaxf(fmaxf(tmax * smax, tmax * smin), fmaxf(tmin * smax, tmin * smin));
}

// ---------------- kP: 641 blocks x 512 threads ----------------
// blocks 0..511 : vfmean, 8 rows per block (proven fast path)
// blocks 512..639: s-partials — (b, cc): own 32-wide colsum slice (depth 32,
//                  16-way d-parallel) then depth-16 dot -> sp[b][cc][hw]
// block 640     : te min/max
__global__ __launch_bounds__(512)
void kP(const float* __restrict__ vf, const float* __restrict__ vw,
        const float* __restrict__ vb, const float* __restrict__ te,
        float* __restrict__ ws) {
  int bid = blockIdx.x, tid = threadIdx.x;
  int w = tid >> 6, lane = tid & 63;

  if (bid < 512) {
    // vfmean: one (b,c) row per wave, coalesced float4
    int row = bid * 8 + w;                       // 0..4095
    float4 v = ((const float4*)vf)[(size_t)row * 64 + lane];
    float s4 = v.x + v.y + v.z + v.w;
    for (int m = 32; m; m >>= 1) s4 += __shfl_xor(s4, m);
    if (lane == 0) ws[WS_VFMEAN + row] = s4 * (1.0f / HW_);
    return;
  }
  if (bid == 640) {
    // te min/max
    float mx = -1e30f, mn = 1e30f;
    #pragma unroll
    for (int i = tid; i < N_ * D_; i += 512) {
      float v = te[i];
      mx = fmaxf(mx, v); mn = fminf(mn, v);
    }
    for (int m = 32; m; m >>= 1) {
      mx = fmaxf(mx, __shfl_xor(mx, m));
      mn = fminf(mn, __shfl_xor(mn, m));
    }
    __shared__ float rx[8], rn[8];
    if (lane == 0) { rx[w] = mx; rn[w] = mn; }
    __syncthreads();
    if (tid == 0) {
      float ax = rx[0], an = rn[0];
      #pragma unroll
      for (int k = 1; k < 8; ++k) { ax = fmaxf(ax, rx[k]); an = fminf(an, rn[k]); }
      ws[WS_TMAX] = ax; ws[WS_TMIN] = an;
    }
    return;
  }
  // s-partial block
  {
    int sidx = bid - 512;                        // 0..127
    int b = sidx >> 3, cc = sidx & 7;
    __shared__ float pcw[16][32];
    __shared__ float cw[32];
    __shared__ float sp2[2][256];
    __shared__ float sbr[8];

    if (cc == 0) {                               // own sum(vb), 16 blocks only
      float v = vb[tid];
      for (int m = 32; m; m >>= 1) v += __shfl_xor(v, m);
      if (lane == 0) sbr[w] = v;
    }
    // colsum slice: c = cc*32 + (tid&31); 16 d-groups of 32
    {
      int cl = tid & 31, dg = tid >> 5;
      int c = cc * 32 + cl;
      float a = 0.f;
      #pragma unroll 8
      for (int d = dg * 32; d < dg * 32 + 32; ++d) a += vw[d * C_ + c];
      pcw[dg][cl] = a;
    }
    __syncthreads();
    if (tid < 32) {
      float a = 0.f;
      #pragma unroll
      for (int k = 0; k < 16; ++k) a += pcw[k][tid];
      cw[tid] = a;
    }
    __syncthreads();
    // depth-16 dot: hw = tid&255, half = tid>>8 covers 16 c's
    {
      int hw = tid & 255, hf = tid >> 8;
      const float* vfb = vf + (size_t)b * C_ * HW_ + (size_t)(cc * 32 + hf * 16) * HW_;
      float acc = 0.f;
      #pragma unroll
      for (int k = 0; k < 16; ++k) acc += vfb[k * HW_ + hw] * cw[hf * 16 + k];
      sp2[hf][hw] = acc;
    }
    __syncthreads();
    if (tid < 256) {
      float s = sp2[0][tid] + sp2[1][tid];
      if (cc == 0) {
        float sbt = sbr[0];
        #pragma unroll
        for (int k = 1; k < 8; ++k) sbt += sbr[k];
        s += sbt;
      }
      ws[WS_SP + (b * 8 + cc) * 256 + tid] = s;
    }
  }
}

// ---------------- kZ: 544 blocks x 256 threads ----------------
// blocks 0..511 : Z partials — reduce 8 sp's -> s (LDS), own min/max + m_b
//                 (bitwise-identical per b; chunk 0 publishes WS_S/WS_M),
//                 then f32x4 exp loop.
// blocks 512..543: vpmean (hidden among Z blocks)
__global__ __launch_bounds__(256)
void kZ(const float* __restrict__ vw, const float* __restrict__ vb,
        const float* __restrict__ te, float* __restrict__ ws) {
  int bid = blockIdx.x, tid = threadIdx.x;
  if (bid < 512) {
    int b = bid >> 5, chunk = bid & 31;
    __shared__ __align__(16) float sl[HW_];
    __shared__ float r3[4], r4[4], part[4];
    float sv = 0.f;
    #pragma unroll
    for (int p = 0; p < 8; ++p) sv += ws[WS_SP + (b * 8 + p) * 256 + tid];
    sl[tid] = sv;
    float smx = sv, smn = sv;
    for (int m = 32; m; m >>= 1) {
      smx = fmaxf(smx, __shfl_xor(smx, m));
      smn = fminf(smn, __shfl_xor(smn, m));
    }
    int w = tid >> 6;
    if ((tid & 63) == 0) { r3[w] = smx; r4[w] = smn; }
    __syncthreads();
    smx = fmaxf(fmaxf(r3[0], r3[1]), fmaxf(r3[2], r3[3]));
    smn = fminf(fminf(r4[0], r4[1]), fminf(r4[2], r4[3]));
    float m = corner(ws[WS_TMAX], ws[WS_TMIN], smx, smn);
    if (chunk == 0) {
      ws[WS_S + b * HW_ + tid] = sv;
      if (tid == 0) ws[WS_M + b] = m;
    }
    float t = te[chunk * 256 + tid];
    const f32x4* sl4 = (const f32x4*)sl;
    float a0 = 0.f, a1 = 0.f, a2 = 0.f, a3 = 0.f;
    #pragma unroll 8
    for (int h = 0; h < HW_ / 4; ++h) {
      f32x4 s4 = sl4[h];
      a0 += __expf(t * s4.x - m);
      a1 += __expf(t * s4.y - m);
      a2 += __expf(t * s4.z - m);
      a3 += __expf(t * s4.w - m);
    }
    float z = (a0 + a1) + (a2 + a3);
    for (int mm = 32; mm; mm >>= 1) z += __shfl_xor(z, mm);
    if ((tid & 63) == 0) part[tid >> 6] = z;
    __syncthreads();
    if (tid == 0) ws[WS_ZP + bid] = part[0] + part[1] + part[2] + part[3];
    return;
  }
  // vpmean[b,dd] = dot(vfmean[b,:], vw[dd,:]) + vb[dd]
  {
    int id = (bid - 512) * 256 + tid;
    int b = id >> 9, dd = id & (D_ - 1);
    __shared__ __align__(16) float vfm[C_];
    vfm[tid] = ws[WS_VFMEAN + b * C_ + tid];
    __syncthreads();
    float acc = vb[dd];
    const f32x4* row4 = (const f32x4*)(vw + (size_t)dd * C_);
    const f32x4* v4   = (const f32x4*)vfm;
    #pragma unroll 8
    for (int c4 = 0; c4 < C_ / 4; ++c4) {
      f32x4 wv = row4[c4], av = v4[c4];
      acc += av.x * wv.x + av.y * wv.y + av.z * wv.z + av.w * wv.w;
    }
    ws[WS_VPMEAN + id] = acc;
  }
}

// ---------------- kD: final (blocks 0..31, first), attn (32..2079) ---------
__global__ __launch_bounds__(256)
void kD(const float* __restrict__ te, const float* __restrict__ mtf,
        const float* __restrict__ iw, const float* __restrict__ ib,
        const float* __restrict__ ws, float* __restrict__ out) {
  int bid = blockIdx.x, tid = threadIdx.x;
  if (bid < 32) {
    int id = bid * 256 + tid;
    int b = id >> 9, d = id & (D_ - 1);
    __shared__ __align__(16) float a[D_], p[D_];
    a[tid]       = mtf[b * D_ + tid];
    a[tid + 256] = mtf[b * D_ + tid + 256];
    p[tid]       = ws[WS_VPMEAN + b * D_ + tid];
    p[tid + 256] = ws[WS_VPMEAN + b * D_ + tid + 256];
    __syncthreads();
    float acc = ib[d];
    const f32x4* row4 = (const f32x4*)(iw + (size_t)d * (2 * D_));
    const f32x4* a4 = (const f32x4*)a;
    const f32x4* p4 = (const f32x4*)p;
    #pragma unroll 8
    for (int c4 = 0; c4 < D_ / 4; ++c4) {
      f32x4 w1 = row4[c4],            av = a4[c4];
      f32x4 w2 = row4[D_ / 4 + c4],   pv = p4[c4];
      acc += av.x * w1.x + av.y * w1.y + av.z * w1.z + av.w * w1.w;
      acc += pv.x * w2.x + pv.y * w2.y + pv.z * w2.z + pv.w * w2.w;
    }
    out[id] = acc;
    return;
  }
  // attn: 2048 blocks x 64 rows each, nontemporal stores
  int r0 = (bid - 32) * 64;
  int b = r0 >> 13;
  __shared__ __align__(16) float sl[HW_];
  __shared__ float sinvZ;
  sl[tid] = ws[WS_S + b * HW_ + tid];
  if (tid < 32) {
    float pz = ws[WS_ZP + b * 32 + tid];
    #pragma unroll
    for (int m = 16; m; m >>= 1) pz += __shfl_xor(pz, m);
    if (tid == 0) sinvZ = 1.0f / pz;
  }
  __syncthreads();
  float m = ws[WS_M + b];
  float invZ = sinvZ;
  int lane = tid & 63;
  int w = tid >> 6;
  float4 sv = ((const float4*)sl)[lane];
  float* attn = out + N_ * D_;
  #pragma unroll 4
  for (int k = 0; k < 16; ++k) {
    int row = r0 + w + k * 4;
    float t = te[row & (N_ * D_ - 1)];
    f32x4 o;
    o.x = __expf(t * sv.x - m) * invZ;
    o.y = __expf(t * sv.y - m) * invZ;
    o.z = __expf(t * sv.z - m) * invZ;
    o.w = __expf(t * sv.w - m) * invZ;
    __builtin_nontemporal_store(o, (f32x4*)(attn + (size_t)row * HW_) + lane);
  }
}

extern "C" void kernel_launch(void* const* d_in, const int* in_sizes, int n_in,
                              void* d_out, int out_size, void* d_ws, size_t ws_size,
                              hipStream_t stream) {
  const float* mtf = (const float*)d_in[0];  // masked_text_features [16,512]
  const float* vf  = (const float*)d_in[1];  // visual_features [16,256,16,16]
  const float* te  = (const float*)d_in[2];  // text_embeddings [16,512]
  const float* vw  = (const float*)d_in[3];  // visual_proj_w [512,256]
  const float* vb  = (const float*)d_in[4];  // visual_proj_b [512]
  const float* iw  = (const float*)d_in[5];  // interaction_w [512,1024]
  const float* ib  = (const float*)d_in[6];  // interaction_b [512]
  float* out = (float*)d_out;
  float* ws  = (float*)d_ws;

  kP<<<641,  512, 0, stream>>>(vf, vw, vb, te, ws);
  kZ<<<544,  256, 0, stream>>>(vw, vb, te, ws);
  kD<<<2080, 256, 0, stream>>>(te, mtf, iw, ib, ws, out);
}

// Round 11
// 66.703 us; speedup vs baseline: 1.8347x; 1.0493x over previous
//
#include <hip/hip_runtime.h>

// Shapes (fixed by the reference): B=N=16, C=256, D=512, H=W=16 (HW=256)
#define B_  16
#define N_  16
#define C_  256
#define D_  512
#define HW_ 256

typedef float f32x4 __attribute__((ext_vector_type(4)));

// ws layout (float offsets)
#define WS_SP     0         // 32768 : s partials [16][8][256]
#define WS_S      32768     // 4096  : s[b,hw] (written by chunk-0 Z-blocks)
#define WS_M      36864     // 16    : per-b softmax max
#define WS_TMAX   36880     // 1
#define WS_TMIN   36881     // 1
#define WS_VFMEAN 36884     // 4096
#define WS_VPMEAN 40980     // 8192
#define WS_ZP     49172     // 512   : Z partials, 32 per b

__device__ __forceinline__ float corner(float tmax, float tmin, float smax, float smin) {
  return fmaxf(fmaxf(tmax * smax, tmax * smin), fmaxf(tmin * smax, tmin * smin));
}

// ---------------- kP: 641 blocks x 512 threads (byte-identical to R10) -----
// blocks 0..511 : vfmean, 8 rows per block
// blocks 512..639: s-partials — (b, cc): own 32-wide colsum slice then
//                  depth-16 dot -> sp[b][cc][hw]
// block 640     : te min/max
__global__ __launch_bounds__(512)
void kP(const float* __restrict__ vf, const float* __restrict__ vw,
        const float* __restrict__ vb, const float* __restrict__ te,
        float* __restrict__ ws) {
  int bid = blockIdx.x, tid = threadIdx.x;
  int w = tid >> 6, lane = tid & 63;

  if (bid < 512) {
    int row = bid * 8 + w;                       // 0..4095
    float4 v = ((const float4*)vf)[(size_t)row * 64 + lane];
    float s4 = v.x + v.y + v.z + v.w;
    for (int m = 32; m; m >>= 1) s4 += __shfl_xor(s4, m);
    if (lane == 0) ws[WS_VFMEAN + row] = s4 * (1.0f / HW_);
    return;
  }
  if (bid == 640) {
    float mx = -1e30f, mn = 1e30f;
    #pragma unroll
    for (int i = tid; i < N_ * D_; i += 512) {
      float v = te[i];
      mx = fmaxf(mx, v); mn = fminf(mn, v);
    }
    for (int m = 32; m; m >>= 1) {
      mx = fmaxf(mx, __shfl_xor(mx, m));
      mn = fminf(mn, __shfl_xor(mn, m));
    }
    __shared__ float rx[8], rn[8];
    if (lane == 0) { rx[w] = mx; rn[w] = mn; }
    __syncthreads();
    if (tid == 0) {
      float ax = rx[0], an = rn[0];
      #pragma unroll
      for (int k = 1; k < 8; ++k) { ax = fmaxf(ax, rx[k]); an = fminf(an, rn[k]); }
      ws[WS_TMAX] = ax; ws[WS_TMIN] = an;
    }
    return;
  }
  {
    int sidx = bid - 512;                        // 0..127
    int b = sidx >> 3, cc = sidx & 7;
    __shared__ float pcw[16][32];
    __shared__ float cw[32];
    __shared__ float sp2[2][256];
    __shared__ float sbr[8];

    if (cc == 0) {
      float v = vb[tid];
      for (int m = 32; m; m >>= 1) v += __shfl_xor(v, m);
      if (lane == 0) sbr[w] = v;
    }
    {
      int cl = tid & 31, dg = tid >> 5;
      int c = cc * 32 + cl;
      float a = 0.f;
      #pragma unroll 8
      for (int d = dg * 32; d < dg * 32 + 32; ++d) a += vw[d * C_ + c];
      pcw[dg][cl] = a;
    }
    __syncthreads();
    if (tid < 32) {
      float a = 0.f;
      #pragma unroll
      for (int k = 0; k < 16; ++k) a += pcw[k][tid];
      cw[tid] = a;
    }
    __syncthreads();
    {
      int hw = tid & 255, hf = tid >> 8;
      const float* vfb = vf + (size_t)b * C_ * HW_ + (size_t)(cc * 32 + hf * 16) * HW_;
      float acc = 0.f;
      #pragma unroll
      for (int k = 0; k < 16; ++k) acc += vfb[k * HW_ + hw] * cw[hf * 16 + k];
      sp2[hf][hw] = acc;
    }
    __syncthreads();
    if (tid < 256) {
      float s = sp2[0][tid] + sp2[1][tid];
      if (cc == 0) {
        float sbt = sbr[0];
        #pragma unroll
        for (int k = 1; k < 8; ++k) sbt += sbr[k];
        s += sbt;
      }
      ws[WS_SP + (b * 8 + cc) * 256 + tid] = s;
    }
  }
}

// ---------------- kZ: 544 blocks x 256 threads (byte-identical to R10) -----
__global__ __launch_bounds__(256)
void kZ(const float* __restrict__ vw, const float* __restrict__ vb,
        const float* __restrict__ te, float* __restrict__ ws) {
  int bid = blockIdx.x, tid = threadIdx.x;
  if (bid < 512) {
    int b = bid >> 5, chunk = bid & 31;
    __shared__ __align__(16) float sl[HW_];
    __shared__ float r3[4], r4[4], part[4];
    float sv = 0.f;
    #pragma unroll
    for (int p = 0; p < 8; ++p) sv += ws[WS_SP + (b * 8 + p) * 256 + tid];
    sl[tid] = sv;
    float smx = sv, smn = sv;
    for (int m = 32; m; m >>= 1) {
      smx = fmaxf(smx, __shfl_xor(smx, m));
      smn = fminf(smn, __shfl_xor(smn, m));
    }
    int w = tid >> 6;
    if ((tid & 63) == 0) { r3[w] = smx; r4[w] = smn; }
    __syncthreads();
    smx = fmaxf(fmaxf(r3[0], r3[1]), fmaxf(r3[2], r3[3]));
    smn = fminf(fminf(r4[0], r4[1]), fminf(r4[2], r4[3]));
    float m = corner(ws[WS_TMAX], ws[WS_TMIN], smx, smn);
    if (chunk == 0) {
      ws[WS_S + b * HW_ + tid] = sv;
      if (tid == 0) ws[WS_M + b] = m;
    }
    float t = te[chunk * 256 + tid];
    const f32x4* sl4 = (const f32x4*)sl;
    float a0 = 0.f, a1 = 0.f, a2 = 0.f, a3 = 0.f;
    #pragma unroll 8
    for (int h = 0; h < HW_ / 4; ++h) {
      f32x4 s4 = sl4[h];
      a0 += __expf(t * s4.x - m);
      a1 += __expf(t * s4.y - m);
      a2 += __expf(t * s4.z - m);
      a3 += __expf(t * s4.w - m);
    }
    float z = (a0 + a1) + (a2 + a3);
    for (int mm = 32; mm; mm >>= 1) z += __shfl_xor(z, mm);
    if ((tid & 63) == 0) part[tid >> 6] = z;
    __syncthreads();
    if (tid == 0) ws[WS_ZP + bid] = part[0] + part[1] + part[2] + part[3];
    return;
  }
  {
    int id = (bid - 512) * 256 + tid;
    int b = id >> 9, dd = id & (D_ - 1);
    __shared__ __align__(16) float vfm[C_];
    vfm[tid] = ws[WS_VFMEAN + b * C_ + tid];
    __syncthreads();
    float acc = vb[dd];
    const f32x4* row4 = (const f32x4*)(vw + (size_t)dd * C_);
    const f32x4* v4   = (const f32x4*)vfm;
    #pragma unroll 8
    for (int c4 = 0; c4 < C_ / 4; ++c4) {
      f32x4 wv = row4[c4], av = v4[c4];
      acc += av.x * wv.x + av.y * wv.y + av.z * wv.z + av.w * wv.w;
    }
    ws[WS_VPMEAN + id] = acc;
  }
}

// ---------------- kD: final (0..31), attn (32..2079) — PLAIN cached stores -
__global__ __launch_bounds__(256)
void kD(const float* __restrict__ te, const float* __restrict__ mtf,
        const float* __restrict__ iw, const float* __restrict__ ib,
        const float* __restrict__ ws, float* __restrict__ out) {
  int bid = blockIdx.x, tid = threadIdx.x;
  if (bid < 32) {
    int id = bid * 256 + tid;
    int b = id >> 9, d = id & (D_ - 1);
    __shared__ __align__(16) float a[D_], p[D_];
    a[tid]       = mtf[b * D_ + tid];
    a[tid + 256] = mtf[b * D_ + tid + 256];
    p[tid]       = ws[WS_VPMEAN + b * D_ + tid];
    p[tid + 256] = ws[WS_VPMEAN + b * D_ + tid + 256];
    __syncthreads();
    float acc = ib[d];
    const f32x4* row4 = (const f32x4*)(iw + (size_t)d * (2 * D_));
    const f32x4* a4 = (const f32x4*)a;
    const f32x4* p4 = (const f32x4*)p;
    #pragma unroll 8
    for (int c4 = 0; c4 < D_ / 4; ++c4) {
      f32x4 w1 = row4[c4],            av = a4[c4];
      f32x4 w2 = row4[D_ / 4 + c4],   pv = p4[c4];
      acc += av.x * w1.x + av.y * w1.y + av.z * w1.z + av.w * w1.w;
      acc += pv.x * w2.x + pv.y * w2.y + pv.z * w2.z + pv.w * w2.w;
    }
    out[id] = acc;
    return;
  }
  // attn: 2048 blocks x 64 rows each, PLAIN stores (L2/L3-cached; 134MB < L3)
  int r0 = (bid - 32) * 64;
  int b = r0 >> 13;
  __shared__ __align__(16) float sl[HW_];
  __shared__ float sinvZ;
  sl[tid] = ws[WS_S + b * HW_ + tid];
  if (tid < 32) {
    float pz = ws[WS_ZP + b * 32 + tid];
    #pragma unroll
    for (int m = 16; m; m >>= 1) pz += __shfl_xor(pz, m);
    if (tid == 0) sinvZ = 1.0f / pz;
  }
  __syncthreads();
  float m = ws[WS_M + b];
  float invZ = sinvZ;
  int lane = tid & 63;
  int w = tid >> 6;
  float4 sv = ((const float4*)sl)[lane];
  float* attn = out + N_ * D_;
  #pragma unroll 4
  for (int k = 0; k < 16; ++k) {
    int row = r0 + w + k * 4;
    float t = te[row & (N_ * D_ - 1)];
    f32x4 o;
    o.x = __expf(t * sv.x - m) * invZ;
    o.y = __expf(t * sv.y - m) * invZ;
    o.z = __expf(t * sv.z - m) * invZ;
    o.w = __expf(t * sv.w - m) * invZ;
    ((f32x4*)(attn + (size_t)row * HW_))[lane] = o;
  }
}

extern "C" void kernel_launch(void* const* d_in, const int* in_sizes, int n_in,
                              void* d_out, int out_size, void* d_ws, size_t ws_size,
                              hipStream_t stream) {
  const float* mtf = (const float*)d_in[0];  // masked_text_features [16,512]
  const float* vf  = (const float*)d_in[1];  // visual_features [16,256,16,16]
  const float* te  = (const float*)d_in[2];  // text_embeddings [16,512]
  const float* vw  = (const float*)d_in[3];  // visual_proj_w [512,256]
  const float* vb  = (const float*)d_in[4];  // visual_proj_b [512]
  const float* iw  = (const float*)d_in[5];  // interaction_w [512,1024]
  const float* ib  = (const float*)d_in[6];  // interaction_b [512]
  float* out = (float*)d_out;
  float* ws  = (float*)d_ws;

  kP<<<641,  512, 0, stream>>>(vf, vw, vb, te, ws);
  kZ<<<544,  256, 0, stream>>>(vw, vb, te, ws);
  kD<<<2080, 256, 0, stream>>>(te, mtf, iw, ib, ws, out);
}